// Round 7
// baseline (50.416 us; speedup 1.0000x reference)
//
#include <hip/hip_runtime.h>

#define SQ 1024
#define DM 1024
#define HD 64
#define NBH 64   // BATCH*NH

typedef __attribute__((ext_vector_type(8))) _Float16 v8h;
typedef __attribute__((ext_vector_type(4))) float v4f;
typedef __attribute__((ext_vector_type(2))) __fp16 v2fp16;
typedef __attribute__((ext_vector_type(4))) unsigned int v4u;

typedef __attribute__((address_space(3))) void as3_void;
typedef __attribute__((address_space(1))) const void as1_cvoid;

__device__ __forceinline__ v4f mfma_f16(v8h a, v8h b, v4f c) {
  return __builtin_amdgcn_mfma_f32_16x16x32_f16(a, b, c, 0, 0, 0);
}

__device__ __forceinline__ void gload16(const _Float16* g, v8h* l) {
  __builtin_amdgcn_global_load_lds((as1_cvoid*)g, (as3_void*)l, 16, 0, 0);
}

// Build fp16 Q, K' = 0.125*k + rel_k[s], and transposed V'^T where V' = v + rel_v[s].
// Layouts: Qh/Kh: [bh][s][d] (d contiguous, 64), Vth: [bh][d][s] (s contiguous, 1024).
__global__ __launch_bounds__(256) void prep_kernel(
    const float* __restrict__ q, const float* __restrict__ k, const float* __restrict__ v,
    const float* __restrict__ relk, const float* __restrict__ relv,
    _Float16* __restrict__ Qh, _Float16* __restrict__ Kh,
    _Float16* __restrict__ Vth)
{
  __shared__ float vt[64][65];
  int blk = blockIdx.x;            // bh*16 + stile
  int st = blk & 15;
  int bh = blk >> 4;
  int b = bh >> 4, h = bh & 15;
  int s0 = st * 64;
  int t = (int)threadIdx.x;
  int d = t & 63, sl4 = t >> 6;    // 0..3
  const float scale = 0.125f;

  #pragma unroll
  for (int i = 0; i < 16; ++i) {
    int sl = sl4 + i * 4;
    int s = s0 + sl;
    size_t gidx = ((size_t)(b * SQ + s)) * DM + h * HD + d;
    float qv = q[gidx];
    float kv = k[gidx] * scale + relk[s * HD + d];
    float vv = v[gidx] + relv[s * HD + d];
    size_t widx = ((size_t)(bh * SQ + s)) * HD + d;
    Qh[widx] = (_Float16)qv;
    Kh[widx] = (_Float16)kv;
    vt[sl][d] = vv;
  }
  __syncthreads();
  int sl = t & 63, d4 = t >> 6;
  #pragma unroll
  for (int i = 0; i < 16; ++i) {
    int dd = d4 + i * 4;
    Vth[((size_t)(bh * HD + dd)) * SQ + s0 + sl] = (_Float16)vt[sl][dd];
  }
}

// Flash attention fwd. Grid 512 blocks (XCD-swizzled: 8 XCDs x 64), 4 waves/block.
// Wave owns 32 q-rows (2 groups of 16). KV tiles of 64, double-buffered in LDS,
// staged by global_load_lds (linear LDS dest, XOR-swizzle applied on the GLOBAL
// source granule; read side uses the same XOR -> conflict-free). 2-phase
// pipeline: stage(t+1) issued before compute(t), one barrier (vmcnt drain)/tile.
// QK^T uses a permuted A-row -> k mapping so the S^T accumulator is ALREADY in
// PV B-fragment layout: no P LDS roundtrip.
__global__ __launch_bounds__(256) void attn_kernel(
    const _Float16* __restrict__ Qh, const _Float16* __restrict__ Kh,
    const _Float16* __restrict__ Vth, float* __restrict__ out)
{
  // granule (row, gr) of the logical tile lives at LDS granule row*8 + (gr ^ f(row)),
  // f(row) = (row&3) | ((row>>3 & 1) << 2). Achieved by pre-swizzling the SOURCE.
  __shared__ v8h KlG[2][512];   // K' tile  [krow][d]  2 x 8KB
  __shared__ v8h VlG[2][512];   // V'^T tile [d][kcol] 2 x 8KB

  int tid = (int)threadIdx.x;
  int lane = tid & 63, w = tid >> 6;
  int g = lane >> 4, r15 = lane & 15;
  // bijective XCD swizzle: 512 = 8 XCDs x 64; each XCD gets 8 whole bh (2MB KV < 4MB L2)
  int bid = (int)blockIdx.x;
  int wk = (bid & 7) * 64 + (bid >> 3);
  int bh = wk >> 3, qt = wk & 7;
  int b = bh >> 4, h = bh & 15;
  int q0 = qt * 128 + w * 32;

  // Q B-frags for 2 groups: col=q=r15, contraction d = 8g+j (+32 for [1])
  v8h aq[2][2];
  #pragma unroll
  for (int t = 0; t < 2; ++t) {
    const _Float16* qb = Qh + ((size_t)(bh * SQ + q0 + 16 * t + r15)) * HD;
    aq[t][0] = *(const v8h*)(qb + g * 8);
    aq[t][1] = *(const v8h*)(qb + 32 + g * 8);
  }

  const _Float16* kb = Kh + (size_t)bh * SQ * HD;
  const _Float16* vb = Vth + (size_t)bh * HD * SQ;

  // ---- staging precompute: LDS granule G = w*128 + j*64 + lane (linear dest),
  // source granule = (row, gr ^ f(row)) of the logical tile ----
  size_t kOff[2], vOff[2];
  int ldsG[2];
  #pragma unroll
  for (int j = 0; j < 2; ++j) {
    int G = w * 128 + j * 64 + lane;
    int row = G >> 3, gr = G & 7;
    int fs = (row & 3) | (((row >> 3) & 1) << 2);
    int src = gr ^ fs;
    kOff[j] = (size_t)row * HD + src * 8;
    vOff[j] = (size_t)row * SQ + src * 8;
    ldsG[j] = w * 128 + j * 64;
  }

  v4f o[2][4];
  #pragma unroll
  for (int t = 0; t < 2; ++t)
    #pragma unroll
    for (int c = 0; c < 4; ++c) o[t][c] = (v4f){0.f, 0.f, 0.f, 0.f};
  float m[2] = {-3.0e38f, -3.0e38f}, l[2] = {0.f, 0.f};

  // K-frag read rows (permuted): A-row r15 of chunk c holds K-row krow[c]
  // k_phys(c,m) = 32*(c>>1) + 8*(m>>2) + 4*(c&1) + (m&3), m = r15
  int krow[4];
  #pragma unroll
  for (int c = 0; c < 4; ++c)
    krow[c] = ((c >> 1) << 5) + ((r15 >> 2) << 3) + ((c & 1) << 2) + (r15 & 3);
  int fk = (r15 & 3) | (((r15 >> 2) & 1) << 2);   // f(krow[c]) for all c
  int fv = (r15 & 3) | (((r15 >> 3) & 1) << 2);   // f(16c + r15) for all c

  // ---- prologue: stage tile 0 ----
  #pragma unroll
  for (int j = 0; j < 2; ++j) {
    gload16(kb + kOff[j], &KlG[0][ldsG[j]]);
    gload16(vb + vOff[j], &VlG[0][ldsG[j]]);
  }
  __syncthreads();   // implicit vmcnt(0) drain + barrier

  for (int t0 = 0; t0 < SQ / 64; ++t0) {
    int cur = t0 & 1;
    // ---- issue next tile's loads into the other buffer (hidden under compute) ----
    if (t0 < SQ / 64 - 1) {
      size_t kT = (size_t)(t0 + 1) * 64 * HD;
      size_t vT = (size_t)(t0 + 1) * 64;
      #pragma unroll
      for (int j = 0; j < 2; ++j) {
        gload16(kb + kT + kOff[j], &KlG[cur ^ 1][ldsG[j]]);
        gload16(vb + vT + vOff[j], &VlG[cur ^ 1][ldsG[j]]);
      }
    }

    // ---- S^T = K'.Q^T with permuted k rows; s[t][c][r] = P-pre[q=r15][k_phys(c,4g+r)] ----
    v4f s[2][4];
    #pragma unroll
    for (int c = 0; c < 4; ++c) {
      v8h kf0 = KlG[cur][krow[c] * 8 + (g ^ fk)];
      v8h kf1 = KlG[cur][krow[c] * 8 + ((4 | g) ^ fk)];
      v4f z0 = (v4f){0.f, 0.f, 0.f, 0.f};
      v4f z1 = (v4f){0.f, 0.f, 0.f, 0.f};
      z0 = mfma_f16(kf0, aq[0][0], z0);
      z0 = mfma_f16(kf1, aq[0][1], z0);
      z1 = mfma_f16(kf0, aq[1][0], z1);
      z1 = mfma_f16(kf1, aq[1][1], z1);
      s[0][c] = z0;
      s[1][c] = z1;
    }

    // ---- online softmax, defer-max (T13), per-lane l partials ----
    #pragma unroll
    for (int t = 0; t < 2; ++t) {
      float pm = s[t][0][0];
      #pragma unroll
      for (int c = 0; c < 4; ++c)
        #pragma unroll
        for (int r = 0; r < 4; ++r)
          pm = fmaxf(pm, s[t][c][r]);
      if (!__all(pm - m[t] <= 8.f)) {
        pm = fmaxf(pm, __shfl_xor(pm, 16));
        pm = fmaxf(pm, __shfl_xor(pm, 32));
        float mnew = fmaxf(m[t], pm);
        float sc = __expf(m[t] - mnew);
        m[t] = mnew;
        l[t] *= sc;
        #pragma unroll
        for (int c = 0; c < 4; ++c) o[t][c] *= sc;
      }
      float rs = 0.f;
      #pragma unroll
      for (int c = 0; c < 4; ++c)
        #pragma unroll
        for (int r = 0; r < 4; ++r) {
          float p = __expf(s[t][c][r] - m[t]);
          s[t][c][r] = p;
          rs += p;
        }
      l[t] += rs;
    }

    // ---- pack P in-lane: acc IS the PV B-frag layout (k-slot 8g+j / 32+8g+j) ----
    v8h pb0[2], pb1[2];
    #pragma unroll
    for (int t = 0; t < 2; ++t) {
      v4u w0, w1;
      w0[0] = __builtin_bit_cast(unsigned int, __builtin_amdgcn_cvt_pkrtz(s[t][0][0], s[t][0][1]));
      w0[1] = __builtin_bit_cast(unsigned int, __builtin_amdgcn_cvt_pkrtz(s[t][0][2], s[t][0][3]));
      w0[2] = __builtin_bit_cast(unsigned int, __builtin_amdgcn_cvt_pkrtz(s[t][1][0], s[t][1][1]));
      w0[3] = __builtin_bit_cast(unsigned int, __builtin_amdgcn_cvt_pkrtz(s[t][1][2], s[t][1][3]));
      w1[0] = __builtin_bit_cast(unsigned int, __builtin_amdgcn_cvt_pkrtz(s[t][2][0], s[t][2][1]));
      w1[1] = __builtin_bit_cast(unsigned int, __builtin_amdgcn_cvt_pkrtz(s[t][2][2], s[t][2][3]));
      w1[2] = __builtin_bit_cast(unsigned int, __builtin_amdgcn_cvt_pkrtz(s[t][3][0], s[t][3][1]));
      w1[3] = __builtin_bit_cast(unsigned int, __builtin_amdgcn_cvt_pkrtz(s[t][3][2], s[t][3][3]));
      pb0[t] = __builtin_bit_cast(v8h, w0);
      pb1[t] = __builtin_bit_cast(v8h, w1);
    }

    // ---- O^T += V'^T . P (V frags shared across both groups) ----
    #pragma unroll
    for (int c = 0; c < 4; ++c) {
      int rv = 16 * c + r15;
      v8h vf0 = VlG[cur][rv * 8 + (g ^ fv)];
      v8h vf1 = VlG[cur][rv * 8 + ((4 | g) ^ fv)];
      #pragma unroll
      for (int t = 0; t < 2; ++t) {
        o[t][c] = mfma_f16(vf0, pb0[t], o[t][c]);
        o[t][c] = mfma_f16(vf1, pb1[t], o[t][c]);
      }
    }

    __syncthreads();   // tile boundary: drains vmcnt(0) (next tile staged) + barrier
  }

  // ---- epilogue: reduce l across half-rows, normalize, vectorized stores ----
  #pragma unroll
  for (int t = 0; t < 2; ++t) {
    float lr = l[t];
    lr += __shfl_xor(lr, 16);
    lr += __shfl_xor(lr, 32);
    float inv = 1.f / lr;
    int qrow = q0 + 16 * t + r15;
    #pragma unroll
    for (int c = 0; c < 4; ++c) {
      v4f res = o[t][c] * inv;
      *(v4f*)(&out[((size_t)(b * SQ + qrow)) * DM + h * HD + 16 * c + 4 * g]) = res;
    }
  }
}

extern "C" void kernel_launch(void* const* d_in, const int* in_sizes, int n_in,
                              void* d_out, int out_size, void* d_ws, size_t ws_size,
                              hipStream_t stream) {
  const float* q = (const float*)d_in[0];
  const float* k = (const float*)d_in[1];
  const float* v = (const float*)d_in[2];
  const float* relk = (const float*)d_in[3];
  const float* relv = (const float*)d_in[4];

  _Float16* Qh = (_Float16*)d_ws;
  _Float16* Kh = Qh + (size_t)NBH * SQ * HD;
  _Float16* Vth = Kh + (size_t)NBH * SQ * HD;

  prep_kernel<<<dim3(NBH * (SQ / 64)), dim3(256), 0, stream>>>(q, k, v, relk, relv, Qh, Kh, Vth);
  attn_kernel<<<dim3(512), dim3(256), 0, stream>>>(Qh, Kh, Vth, (float*)d_out);
}

// Round 8
// 50.144 us; speedup vs baseline: 1.0054x; 1.0054x over previous
//
#include <hip/hip_runtime.h>

#define SQ 1024
#define DM 1024
#define HD 64
#define NBH 64   // BATCH*NH

typedef __attribute__((ext_vector_type(8))) _Float16 v8h;
typedef __attribute__((ext_vector_type(4))) float v4f;
typedef __attribute__((ext_vector_type(2))) __fp16 v2fp16;
typedef __attribute__((ext_vector_type(4))) unsigned int v4u;

typedef __attribute__((address_space(3))) void as3_void;
typedef __attribute__((address_space(1))) const void as1_cvoid;

__device__ __forceinline__ v4f mfma_f16(v8h a, v8h b, v4f c) {
  return __builtin_amdgcn_mfma_f32_16x16x32_f16(a, b, c, 0, 0, 0);
}

__device__ __forceinline__ void gload16(const _Float16* g, v8h* l) {
  __builtin_amdgcn_global_load_lds((as1_cvoid*)g, (as3_void*)l, 16, 0, 0);
}

// Build fp16 Q, K' = 0.125*k + rel_k[s], and transposed V'^T where V' = v + rel_v[s].
// Layouts: Qh/Kh: [bh][s][d] (d contiguous, 64), Vth: [bh][d][s] (s contiguous, 1024).
__global__ __launch_bounds__(256) void prep_kernel(
    const float* __restrict__ q, const float* __restrict__ k, const float* __restrict__ v,
    const float* __restrict__ relk, const float* __restrict__ relv,
    _Float16* __restrict__ Qh, _Float16* __restrict__ Kh,
    _Float16* __restrict__ Vth)
{
  __shared__ float vt[64][65];
  int blk = blockIdx.x;            // bh*16 + stile
  int st = blk & 15;
  int bh = blk >> 4;
  int b = bh >> 4, h = bh & 15;
  int s0 = st * 64;
  int t = (int)threadIdx.x;
  int d = t & 63, sl4 = t >> 6;    // 0..3
  const float scale = 0.125f;

  #pragma unroll
  for (int i = 0; i < 16; ++i) {
    int sl = sl4 + i * 4;
    int s = s0 + sl;
    size_t gidx = ((size_t)(b * SQ + s)) * DM + h * HD + d;
    float qv = q[gidx];
    float kv = k[gidx] * scale + relk[s * HD + d];
    float vv = v[gidx] + relv[s * HD + d];
    size_t widx = ((size_t)(bh * SQ + s)) * HD + d;
    Qh[widx] = (_Float16)qv;
    Kh[widx] = (_Float16)kv;
    vt[sl][d] = vv;
  }
  __syncthreads();
  int sl = t & 63, d4 = t >> 6;
  #pragma unroll
  for (int i = 0; i < 16; ++i) {
    int dd = d4 + i * 4;
    Vth[((size_t)(bh * HD + dd)) * SQ + s0 + sl] = (_Float16)vt[sl][dd];
  }
}

// QK^T of one staged K-tile (permuted A-row -> k mapping): s[t][c][r] already
// in PV B-fragment layout.
#define QK_TILE(S, BUFBASE)                                        \
  {                                                                \
    _Pragma("unroll")                                              \
    for (int c = 0; c < 4; ++c) {                                  \
      v8h kf0 = KlG[(BUFBASE) + krow[c] * 8 + (g ^ fk)];           \
      v8h kf1 = KlG[(BUFBASE) + krow[c] * 8 + ((4 | g) ^ fk)];     \
      v4f z0 = (v4f){0.f, 0.f, 0.f, 0.f};                          \
      v4f z1 = (v4f){0.f, 0.f, 0.f, 0.f};                          \
      z0 = mfma_f16(kf0, aq[0][0], z0);                            \
      z0 = mfma_f16(kf1, aq[0][1], z0);                            \
      z1 = mfma_f16(kf0, aq[1][0], z1);                            \
      z1 = mfma_f16(kf1, aq[1][1], z1);                            \
      S[0][c] = z0;                                                \
      S[1][c] = z1;                                                \
    }                                                              \
  }

// Flash attention fwd. Grid 512 blocks (XCD-swizzled), 4 waves/block, wave owns
// 32 q-rows (2 groups of 16). KV tiles of 64, TRIPLE-buffered LDS staged by
// global_load_lds two tiles ahead (linear LDS dest, XOR swizzle pre-applied on
// the global source granule; same XOR on reads -> conflict-free).
// Pipeline per iter: issue stage(t+2) | QK(t+1) | softmax(t) | PV(t) | barrier.
// QK(t+1)'s MFMAs/ds_reads overlap softmax(t)'s VALU work.
__global__ __launch_bounds__(256) void attn_kernel(
    const _Float16* __restrict__ Qh, const _Float16* __restrict__ Kh,
    const _Float16* __restrict__ Vth, float* __restrict__ out)
{
  __shared__ v8h KlG[3 * 512];   // K' tiles  [krow][d]  3 x 8KB
  __shared__ v8h VlG[3 * 512];   // V'^T tiles [d][kcol] 3 x 8KB

  int tid = (int)threadIdx.x;
  int lane = tid & 63, w = tid >> 6;
  int g = lane >> 4, r15 = lane & 15;
  // bijective XCD swizzle: 512 = 8 XCDs x 64; each XCD gets 8 whole bh (2MB KV < 4MB L2)
  int bid = (int)blockIdx.x;
  int wk = (bid & 7) * 64 + (bid >> 3);
  int bh = wk >> 3, qt = wk & 7;
  int b = bh >> 4, h = bh & 15;
  int q0 = qt * 128 + w * 32;

  // Q B-frags for 2 groups: col=q=r15, contraction d = 8g+j (+32 for [1])
  v8h aq[2][2];
  #pragma unroll
  for (int t = 0; t < 2; ++t) {
    const _Float16* qb = Qh + ((size_t)(bh * SQ + q0 + 16 * t + r15)) * HD;
    aq[t][0] = *(const v8h*)(qb + g * 8);
    aq[t][1] = *(const v8h*)(qb + 32 + g * 8);
  }

  const _Float16* kb = Kh + (size_t)bh * SQ * HD;
  const _Float16* vb = Vth + (size_t)bh * HD * SQ;

  // staging precompute: LDS granule G = w*128 + j*64 + lane (linear dest),
  // source granule = (row, gr ^ f(row)) of the logical tile
  size_t kOff[2], vOff[2];
  int ldsG[2];
  #pragma unroll
  for (int j = 0; j < 2; ++j) {
    int G = w * 128 + j * 64 + lane;
    int row = G >> 3, gr = G & 7;
    int fs = (row & 3) | (((row >> 3) & 1) << 2);
    int src = gr ^ fs;
    kOff[j] = (size_t)row * HD + src * 8;
    vOff[j] = (size_t)row * SQ + src * 8;
    ldsG[j] = w * 128 + j * 64;
  }

  v4f o[2][4];
  #pragma unroll
  for (int t = 0; t < 2; ++t)
    #pragma unroll
    for (int c = 0; c < 4; ++c) o[t][c] = (v4f){0.f, 0.f, 0.f, 0.f};
  float m[2] = {-3.0e38f, -3.0e38f}, l[2] = {0.f, 0.f};

  // K-frag read rows (permuted): k_phys(c,m) = 32*(c>>1) + 8*(m>>2) + 4*(c&1) + (m&3)
  int krow[4];
  #pragma unroll
  for (int c = 0; c < 4; ++c)
    krow[c] = ((c >> 1) << 5) + ((r15 >> 2) << 3) + ((c & 1) << 2) + (r15 & 3);
  int fk = (r15 & 3) | (((r15 >> 2) & 1) << 2);   // f(krow[c]) for all c
  int fv = (r15 & 3) | (((r15 >> 3) & 1) << 2);   // f(16c + r15) for all c

  const int NT = SQ / 64;

  // ---- prologue: stage tiles 0 and 1 ----
  #pragma unroll
  for (int j = 0; j < 2; ++j) {
    gload16(kb + kOff[j], &KlG[ldsG[j]]);
    gload16(vb + vOff[j], &VlG[ldsG[j]]);
  }
  #pragma unroll
  for (int j = 0; j < 2; ++j) {
    gload16(kb + (size_t)64 * HD + kOff[j], &KlG[512 + ldsG[j]]);
    gload16(vb + 64 + vOff[j], &VlG[512 + ldsG[j]]);
  }
  __syncthreads();   // drains vmcnt(0): tiles 0,1 resident

  v4f s_cur[2][4], s_next[2][4];
  QK_TILE(s_cur, 0);

  #pragma unroll 2
  for (int t0 = 0; t0 < NT; ++t0) {
    int bstage = (t0 + 2) % 3, bnext = (t0 + 1) % 3, bcur = t0 % 3;

    // ---- issue stage(t+2): hidden under this and next iteration's compute ----
    if (t0 + 2 < NT) {
      size_t kT = (size_t)(t0 + 2) * 64 * HD;
      size_t vT = (size_t)(t0 + 2) * 64;
      #pragma unroll
      for (int j = 0; j < 2; ++j) {
        gload16(kb + kT + kOff[j], &KlG[bstage * 512 + ldsG[j]]);
        gload16(vb + vT + vOff[j], &VlG[bstage * 512 + ldsG[j]]);
      }
    }

    // ---- QK(t+1): MFMA+ds_read overlap the softmax below ----
    if (t0 + 1 < NT) QK_TILE(s_next, bnext * 512);

    // ---- online softmax on s_cur, defer-max (T13), per-lane l partials ----
    #pragma unroll
    for (int t = 0; t < 2; ++t) {
      float pm = s_cur[t][0][0];
      #pragma unroll
      for (int c = 0; c < 4; ++c)
        #pragma unroll
        for (int r = 0; r < 4; ++r)
          pm = fmaxf(pm, s_cur[t][c][r]);
      if (!__all(pm - m[t] <= 8.f)) {
        pm = fmaxf(pm, __shfl_xor(pm, 16));
        pm = fmaxf(pm, __shfl_xor(pm, 32));
        float mnew = fmaxf(m[t], pm);
        float sc = __expf(m[t] - mnew);
        m[t] = mnew;
        l[t] *= sc;
        #pragma unroll
        for (int c = 0; c < 4; ++c) o[t][c] *= sc;
      }
      float rs = 0.f;
      #pragma unroll
      for (int c = 0; c < 4; ++c)
        #pragma unroll
        for (int r = 0; r < 4; ++r) {
          float p = __expf(s_cur[t][c][r] - m[t]);
          s_cur[t][c][r] = p;
          rs += p;
        }
      l[t] += rs;
    }

    // ---- pack P in-lane: acc IS the PV B-frag layout ----
    v8h pb0[2], pb1[2];
    #pragma unroll
    for (int t = 0; t < 2; ++t) {
      v4u w0, w1;
      w0[0] = __builtin_bit_cast(unsigned int, __builtin_amdgcn_cvt_pkrtz(s_cur[t][0][0], s_cur[t][0][1]));
      w0[1] = __builtin_bit_cast(unsigned int, __builtin_amdgcn_cvt_pkrtz(s_cur[t][0][2], s_cur[t][0][3]));
      w0[2] = __builtin_bit_cast(unsigned int, __builtin_amdgcn_cvt_pkrtz(s_cur[t][1][0], s_cur[t][1][1]));
      w0[3] = __builtin_bit_cast(unsigned int, __builtin_amdgcn_cvt_pkrtz(s_cur[t][1][2], s_cur[t][1][3]));
      w1[0] = __builtin_bit_cast(unsigned int, __builtin_amdgcn_cvt_pkrtz(s_cur[t][2][0], s_cur[t][2][1]));
      w1[1] = __builtin_bit_cast(unsigned int, __builtin_amdgcn_cvt_pkrtz(s_cur[t][2][2], s_cur[t][2][3]));
      w1[2] = __builtin_bit_cast(unsigned int, __builtin_amdgcn_cvt_pkrtz(s_cur[t][3][0], s_cur[t][3][1]));
      w1[3] = __builtin_bit_cast(unsigned int, __builtin_amdgcn_cvt_pkrtz(s_cur[t][3][2], s_cur[t][3][3]));
      pb0[t] = __builtin_bit_cast(v8h, w0);
      pb1[t] = __builtin_bit_cast(v8h, w1);
    }

    // ---- O^T += V'^T . P (V frags shared across both groups) ----
    #pragma unroll
    for (int c = 0; c < 4; ++c) {
      int rv = 16 * c + r15;
      v8h vf0 = VlG[bcur * 512 + rv * 8 + (g ^ fv)];
      v8h vf1 = VlG[bcur * 512 + rv * 8 + ((4 | g) ^ fv)];
      #pragma unroll
      for (int t = 0; t < 2; ++t) {
        o[t][c] = mfma_f16(vf0, pb0[t], o[t][c]);
        o[t][c] = mfma_f16(vf1, pb1[t], o[t][c]);
      }
    }

    __syncthreads();   // tile boundary: protects buf (t+3)%3 reuse; drains stage

    #pragma unroll
    for (int t = 0; t < 2; ++t)
      #pragma unroll
      for (int c = 0; c < 4; ++c)
        s_cur[t][c] = s_next[t][c];
  }

  // ---- epilogue: reduce l across k-slices, normalize, vectorized stores ----
  #pragma unroll
  for (int t = 0; t < 2; ++t) {
    float lr = l[t];
    lr += __shfl_xor(lr, 16);
    lr += __shfl_xor(lr, 32);
    float inv = 1.f / lr;
    int qrow = q0 + 16 * t + r15;
    #pragma unroll
    for (int c = 0; c < 4; ++c) {
      v4f res = o[t][c] * inv;
      *(v4f*)(&out[((size_t)(b * SQ + qrow)) * DM + h * HD + 16 * c + 4 * g]) = res;
    }
  }
}

extern "C" void kernel_launch(void* const* d_in, const int* in_sizes, int n_in,
                              void* d_out, int out_size, void* d_ws, size_t ws_size,
                              hipStream_t stream) {
  const float* q = (const float*)d_in[0];
  const float* k = (const float*)d_in[1];
  const float* v = (const float*)d_in[2];
  const float* relk = (const float*)d_in[3];
  const float* relv = (const float*)d_in[4];

  _Float16* Qh = (_Float16*)d_ws;
  _Float16* Kh = Qh + (size_t)NBH * SQ * HD;
  _Float16* Vth = Kh + (size_t)NBH * SQ * HD;

  prep_kernel<<<dim3(NBH * (SQ / 64)), dim3(256), 0, stream>>>(q, k, v, relk, relv, Qh, Kh, Vth);
  attn_kernel<<<dim3(512), dim3(256), 0, stream>>>(Qh, Kh, Vth, (float*)d_out);
}